// Round 5
// baseline (159.880 us; speedup 1.0000x reference)
//
#include <hip/hip_runtime.h>

#define HH 256
#define WW 256
#define NB 4
#define NC 128
#define HW (HH * WW)

// ---------- bf16 helpers (manual, RNE) ----------
__device__ __forceinline__ float blo(unsigned int u) { return __uint_as_float(u << 16); }
__device__ __forceinline__ float bhi(unsigned int u) { return __uint_as_float(u & 0xffff0000u); }
__device__ __forceinline__ unsigned int bf16_rne(float f) {
    unsigned int u = __float_as_uint(f);
    return (u + 0x7fffu + ((u >> 16) & 1u)) >> 16;  // finite inputs only
}
__device__ __forceinline__ unsigned int pack_bf16(float a, float b) {
    return bf16_rne(a) | (bf16_rne(b) << 16);
}
union U4 { uint4 v; unsigned int w[4]; };

// LDS tile: 64 pixels x 64 uints (bf16 channel-pairs), 16 KB.
// swizzle uses px4 (p bits 2-3) and py parity (p bit 4) -> write phase hits
// 32 distinct banks (2-way only); read phase reads full pixel rows (even).
#define SWZ(p) ((((p) >> 2) & 3) << 2 | ((((p) >> 4) & 1) << 4))
#define LIDX(p, w) (((p) << 6) + ((w) ^ SWZ(p)))

// =====================================================================
// prep4: CHW f32 -> HWC bf16 (scales 0/1/2); bf16 packed BEFORE LDS.
// Tile 4 rows x 16 cols x 128 ch. Conflict-free by construction.
// =====================================================================
__global__ __launch_bounds__(256) void prep4_kernel(
        const float* __restrict__ feat1, const float* __restrict__ feat2,
        unsigned int* __restrict__ s0f1, unsigned int* __restrict__ s0f2,
        unsigned int* __restrict__ d1f1, unsigned int* __restrict__ d1f2,
        unsigned int* __restrict__ d2f1, unsigned int* __restrict__ d2f2) {
    __shared__ unsigned int lds[64 * 64];

    int z = blockIdx.z;
    int b = z & 3;
    const float* src = (z < 4 ? feat1 : feat2) + (size_t)b * NC * HW;
    unsigned int* s0 = (z < 4 ? s0f1 : s0f2);
    unsigned int* d1 = (z < 4 ? d1f1 : d1f2);
    unsigned int* d2 = (z < 4 ? d2f1 : d2f2);

    int tid = threadIdx.x;
    int bx = blockIdx.x;   // 0..15 : 16-col tiles
    int by = blockIdx.y;   // 0..63 : 4-row tiles
    int x0 = bx * 16, y0 = by * 4;

    // ---- load phase: lane = (channel-pair band, float4 pos) ----
    {
        int f4 = tid & 15;
        int py = f4 >> 2, px4 = f4 & 3;
        int cb = tid >> 4;               // 0..15
        const float* lp = src + (size_t)(y0 + py) * WW + x0 + px4 * 4;
        int pbase = py * 16 + px4 * 4;
#pragma unroll
        for (int it = 0; it < 4; ++it) {
            int cpair = it * 16 + cb;    // channels 2*cpair, 2*cpair+1
            const float* pa = lp + (size_t)(2 * cpair) * HW;
            float4 va = *(const float4*)pa;
            float4 vb = *(const float4*)(pa + HW);
            lds[LIDX(pbase + 0, cpair)] = pack_bf16(va.x, vb.x);
            lds[LIDX(pbase + 1, cpair)] = pack_bf16(va.y, vb.y);
            lds[LIDX(pbase + 2, cpair)] = pack_bf16(va.z, vb.z);
            lds[LIDX(pbase + 3, cpair)] = pack_bf16(va.w, vb.w);
        }
    }
    __syncthreads();

    int c8 = tid & 15;   // fixed channel group: uints c8*4..c8*4+3 (8 channels)
    int cw = c8 * 4;

    // ---- s0: read uint4 (fixed channels, swizzled slot), store linear ----
    {
        int pq = tid >> 4;   // 0..15 : col within row
#pragma unroll
        for (int it = 0; it < 4; ++it) {
            int p = it * 16 + pq;
            uint4 u = *(const uint4*)&lds[(p << 6) + (cw ^ SWZ(p))];
            size_t pix = ((size_t)(b * HH + y0 + it) * WW + (x0 + pq));
            *(uint4*)(s0 + pix * 64 + cw) = u;
        }
    }

    // ---- d1: 2x8 quads, average 4 corners in f32 ----
    {
        int dp = tid >> 4;           // 0..15
        int qy = dp >> 3, qx = dp & 7;
        int p00 = (2 * qy) * 16 + 2 * qx;
        U4 u0, u1, u2, u3, o;
        u0.v = *(const uint4*)&lds[(p00 << 6)        + (cw ^ SWZ(p00))];
        u1.v = *(const uint4*)&lds[((p00 + 1) << 6)  + (cw ^ SWZ(p00 + 1))];
        u2.v = *(const uint4*)&lds[((p00 + 16) << 6) + (cw ^ SWZ(p00 + 16))];
        u3.v = *(const uint4*)&lds[((p00 + 17) << 6) + (cw ^ SWZ(p00 + 17))];
#pragma unroll
        for (int j = 0; j < 4; ++j) {
            float lo = blo(u0.w[j]) + blo(u1.w[j]) + blo(u2.w[j]) + blo(u3.w[j]);
            float hi = bhi(u0.w[j]) + bhi(u1.w[j]) + bhi(u2.w[j]) + bhi(u3.w[j]);
            o.w[j] = pack_bf16(0.25f * lo, 0.25f * hi);
        }
        size_t pix = ((size_t)(b * 128 + by * 2 + qy) * 128 + (bx * 8 + qx));
        *(uint4*)(d1 + pix * 64 + cw) = o.v;
    }

    // ---- d2: 4 pixels (rows 1..2, cols 4k+1..4k+2) ----
    if (tid < 64) {
        int dp = tid >> 4;           // 0..3
        int p00 = 16 + 4 * dp + 1;
        U4 u0, u1, u2, u3, o;
        u0.v = *(const uint4*)&lds[(p00 << 6)        + (cw ^ SWZ(p00))];
        u1.v = *(const uint4*)&lds[((p00 + 1) << 6)  + (cw ^ SWZ(p00 + 1))];
        u2.v = *(const uint4*)&lds[((p00 + 16) << 6) + (cw ^ SWZ(p00 + 16))];
        u3.v = *(const uint4*)&lds[((p00 + 17) << 6) + (cw ^ SWZ(p00 + 17))];
#pragma unroll
        for (int j = 0; j < 4; ++j) {
            float lo = blo(u0.w[j]) + blo(u1.w[j]) + blo(u2.w[j]) + blo(u3.w[j]);
            float hi = bhi(u0.w[j]) + bhi(u1.w[j]) + bhi(u2.w[j]) + bhi(u3.w[j]);
            o.w[j] = pack_bf16(0.25f * lo, 0.25f * hi);
        }
        size_t pix = ((size_t)(b * 64 + by) * 64 + (bx * 4 + dp));
        *(uint4*)(d2 + pix * 64 + cw) = o.v;
    }
}

// =====================================================================
// HWC corr: 16 lanes per pixel, one uint4 (8 bf16 ch) per lane.
// =====================================================================
template <int SCALE>
__global__ void corr_hwc(const unsigned int* __restrict__ f1,
                         const unsigned int* __restrict__ f2,
                         const float* __restrict__ offs,
                         float* __restrict__ out) {
    constexpr int S = (SCALE == 0) ? 256 : (SCALE == 1 ? 128 : 64);
    constexpr int LOGS = (SCALE == 0) ? 8 : (SCALE == 1 ? 7 : 6);
    int tid = threadIdx.x;
    int lane = tid & 15;
    int pix = blockIdx.x * 16 + (tid >> 4);
    int b = pix >> (2 * LOGS);
    int p = pix & (S * S - 1);
    int y = p >> LOGS;
    int x = p & (S - 1);

    const float* offx = offs + ((size_t)b * 6 + 2 * SCALE) * (HH * WW);
    const float* offy = offx + HH * WW;
    float dx, dy;
    if constexpr (SCALE == 0) {
        dx = offx[y * WW + x];
        dy = offy[y * WW + x];
    } else if constexpr (SCALE == 1) {
        const float* px = offx + (2 * y) * WW + 2 * x;
        const float* py = offy + (2 * y) * WW + 2 * x;
        dx = 0.125f * (px[0] + px[1] + px[WW] + px[WW + 1]);
        dy = 0.125f * (py[0] + py[1] + py[WW] + py[WW + 1]);
    } else {
        const float* px = offx + (4 * y + 1) * WW + 4 * x + 1;
        const float* py = offy + (4 * y + 1) * WW + 4 * x + 1;
        dx = 0.0625f * (px[0] + px[1] + px[WW] + px[WW + 1]);
        dy = 0.0625f * (py[0] + py[1] + py[WW] + py[WW + 1]);
    }

    float sx = (float)x + dx;
    float sy = (float)y + dy;
    float x0f = floorf(sx), y0f = floorf(sy);
    float wx1 = sx - x0f, wy1 = sy - y0f;
    float wx0 = 1.0f - wx1, wy0 = 1.0f - wy1;
    int x0 = (int)x0f, y0 = (int)y0f;
    int x1 = x0 + 1, y1 = y0 + 1;
    bool vx0 = (x0 >= 0) & (x0 < S);
    bool vx1 = (x1 >= 0) & (x1 < S);
    bool vy0 = (y0 >= 0) & (y0 < S);
    bool vy1 = (y1 >= 0) & (y1 < S);
    float w00 = wy0 * wx0 * (float)(vy0 & vx0);
    float w01 = wy0 * wx1 * (float)(vy0 & vx1);
    float w10 = wy1 * wx0 * (float)(vy1 & vx0);
    float w11 = wy1 * wx1 * (float)(vy1 & vx1);
    int cx0 = min(max(x0, 0), S - 1), cx1 = min(max(x1, 0), S - 1);
    int cy0 = min(max(y0, 0), S - 1), cy1 = min(max(y1, 0), S - 1);
    size_t pb = (size_t)b << (2 * LOGS);
    size_t i00 = pb + (cy0 << LOGS) + cx0, i01 = pb + (cy0 << LOGS) + cx1;
    size_t i10 = pb + (cy1 << LOGS) + cx0, i11 = pb + (cy1 << LOGS) + cx1;

    int lo = lane * 4;
    U4 a, c00, c01, c10, c11;
    a.v   = *(const uint4*)(f1 + ((size_t)pix << 6) + lo);
    c00.v = *(const uint4*)(f2 + (i00 << 6) + lo);
    c01.v = *(const uint4*)(f2 + (i01 << 6) + lo);
    c10.v = *(const uint4*)(f2 + (i10 << 6) + lo);
    c11.v = *(const uint4*)(f2 + (i11 << 6) + lo);

    float acc = 0.0f;
#pragma unroll
    for (int j = 0; j < 4; ++j) {
        float s_lo = w00 * blo(c00.w[j]) + w01 * blo(c01.w[j]) + w10 * blo(c10.w[j]) + w11 * blo(c11.w[j]);
        float s_hi = w00 * bhi(c00.w[j]) + w01 * bhi(c01.w[j]) + w10 * bhi(c10.w[j]) + w11 * bhi(c11.w[j]);
        acc = fmaf(blo(a.w[j]), s_lo, acc);
        acc = fmaf(bhi(a.w[j]), s_hi, acc);
    }
    acc += __shfl_xor(acc, 8);
    acc += __shfl_xor(acc, 4);
    acc += __shfl_xor(acc, 2);
    acc += __shfl_xor(acc, 1);

    if (lane == 0) {
        if constexpr (SCALE == 0) {
            out[((size_t)b * 3) * (HH * WW) + p] = acc;
        } else {
            out[(size_t)b * (S * S) + p] = acc;
        }
    }
}

// ---------------- upsample corr back to 256x256 ----------------
template <int SCALE>
__global__ void up_kernel(const float* __restrict__ corr, float* __restrict__ out) {
    constexpr int S = (SCALE == 1) ? 128 : 64;
    constexpr float R = (float)S / 256.0f;
    int idx = blockIdx.x * blockDim.x + threadIdx.x;
    if (idx >= NB * HH * WW) return;
    int x = idx & 255;
    int t = idx >> 8;
    int y = t & 255;
    int b = t >> 8;
    float srcx = fminf(fmaxf(((float)x + 0.5f) * R - 0.5f, 0.0f), (float)(S - 1));
    float srcy = fminf(fmaxf(((float)y + 0.5f) * R - 0.5f, 0.0f), (float)(S - 1));
    int x0 = (int)srcx;
    int y0 = (int)srcy;
    int x1 = min(x0 + 1, S - 1), y1 = min(y0 + 1, S - 1);
    float wx = srcx - (float)x0, wy = srcy - (float)y0;
    const float* cp = corr + (size_t)b * (S * S);
    float v0 = cp[y0 * S + x0] * (1.0f - wx) + cp[y0 * S + x1] * wx;
    float v1 = cp[y1 * S + x0] * (1.0f - wx) + cp[y1 * S + x1] * wx;
    out[((size_t)b * 3 + SCALE) * (HH * WW) + y * WW + x] = (1.0f - wy) * v0 + wy * v1;
}

extern "C" void kernel_launch(void* const* d_in, const int* in_sizes, int n_in,
                              void* d_out, int out_size, void* d_ws, size_t ws_size,
                              hipStream_t stream) {
    const float* feat1 = (const float*)d_in[0];
    const float* feat2 = (const float*)d_in[1];
    const float* offs  = (const float*)d_in[2];
    float* out = (float*)d_out;

    const size_t n_s0 = (size_t)NB * HH * WW * 64;
    const size_t n_d1 = (size_t)NB * 128 * 128 * 64;
    const size_t n_d2 = (size_t)NB * 64 * 64 * 64;
    const size_t n_c1 = (size_t)NB * 128 * 128;
    const size_t n_c2 = (size_t)NB * 64 * 64;
    const size_t need = (2 * (n_s0 + n_d1 + n_d2) + n_c1 + n_c2) * 4;
    if (ws_size < need) return;

    unsigned int* ws = (unsigned int*)d_ws;
    unsigned int* s0f1 = ws;
    unsigned int* s0f2 = s0f1 + n_s0;
    unsigned int* d1f1 = s0f2 + n_s0;
    unsigned int* d1f2 = d1f1 + n_d1;
    unsigned int* d2f1 = d1f2 + n_d1;
    unsigned int* d2f2 = d2f1 + n_d2;
    float* corr1 = (float*)(d2f2 + n_d2);
    float* corr2 = corr1 + n_c1;

    prep4_kernel<<<dim3(16, 64, 8), 256, 0, stream>>>(feat1, feat2, s0f1, s0f2,
                                                      d1f1, d1f2, d2f1, d2f2);

    corr_hwc<0><<<NB * 65536 / 16, 256, 0, stream>>>(s0f1, s0f2, offs, out);
    corr_hwc<1><<<NB * 16384 / 16, 256, 0, stream>>>(d1f1, d1f2, offs, corr1);
    corr_hwc<2><<<NB * 4096 / 16, 256, 0, stream>>>(d2f1, d2f2, offs, corr2);

    up_kernel<1><<<(NB * HH * WW + 255) / 256, 256, 0, stream>>>(corr1, out);
    up_kernel<2><<<(NB * HH * WW + 255) / 256, 256, 0, stream>>>(corr2, out);
}

// Round 6
// 145.301 us; speedup vs baseline: 1.1003x; 1.1003x over previous
//
#include <hip/hip_runtime.h>

#define HH 256
#define WW 256
#define NB 4
#define NC 128
#define HW (HH * WW)

// ---------- bf16 helpers (manual, RNE) ----------
__device__ __forceinline__ float blo(unsigned int u) { return __uint_as_float(u << 16); }
__device__ __forceinline__ float bhi(unsigned int u) { return __uint_as_float(u & 0xffff0000u); }
__device__ __forceinline__ unsigned int bf16_rne(float f) {
    unsigned int u = __float_as_uint(f);
    return (u + 0x7fffu + ((u >> 16) & 1u)) >> 16;  // finite inputs only
}
__device__ __forceinline__ unsigned int pack_bf16(float a, float b) {
    return bf16_rne(a) | (bf16_rne(b) << 16);
}
union U4 { uint4 v; unsigned int w[4]; };

// =====================================================================
// prep5: CHW f32 -> HWC bf16 scale-0 ONLY. Tile = 1 row x 128 cols x 128ch.
// Global reads: 512B contiguous per wave-load (the round-5 fix).
// LDS: channel-major [cpair(64)][px(128)] uints, 32KB, bf16-packed.
//   write: contiguous ds_write_b128 (conflict-free)
//   read:  b32 with XOR swizzle p ^ ((c8&7)<<2)  -> 2-way (free)
// =====================================================================
__global__ __launch_bounds__(256) void prep5_kernel(
        const float* __restrict__ feat1, const float* __restrict__ feat2,
        unsigned int* __restrict__ s0f1, unsigned int* __restrict__ s0f2) {
    __shared__ unsigned int lds[64 * 128];   // 32 KB

    int z = blockIdx.z;
    int b = z & 3;
    const float* src = (z < 4 ? feat1 : feat2) + (size_t)b * NC * HW;
    unsigned int* s0 = (z < 4 ? s0f1 : s0f2);

    int y  = blockIdx.y;        // 0..255 : row
    int bx = blockIdx.x;        // 0..1   : 128-col half
    int tid = threadIdx.x;
    int w = tid >> 6;           // wave 0..3
    int l = tid & 63;
    int lp = l & 31;            // col float4 position (cols 4*lp..4*lp+3)
    int ch = l >> 5;            // sub-channel-pair select

    const float* rowp = src + (size_t)y * WW + bx * 128 + 4 * lp;

#pragma unroll
    for (int it = 0; it < 8; ++it) {
        int cp = it * 8 + w * 2 + ch;          // channel pair 0..63
        const float* pa = rowp + (size_t)(2 * cp) * HW;
        float4 v0 = *(const float4*)pa;        // channel 2*cp, 512B/32 lanes
        float4 v1 = *(const float4*)(pa + HW); // channel 2*cp+1
        unsigned int h = ((cp >> 2) & 7) << 2;
        U4 u;
        u.w[0] = pack_bf16(v0.x, v1.x);
        u.w[1] = pack_bf16(v0.y, v1.y);
        u.w[2] = pack_bf16(v0.z, v1.z);
        u.w[3] = pack_bf16(v0.w, v1.w);
        *(uint4*)&lds[cp * 128 + ((4 * lp) ^ h)] = u.v;
    }
    __syncthreads();

    int c8 = l & 15;            // channel chunk (8 ch = 4 uints)
    int pq = l >> 4;            // 0..3
    int hr = (c8 & 7) << 2;
#pragma unroll
    for (int it = 0; it < 8; ++it) {
        int p = w * 32 + it * 4 + pq;          // pixel col within 128-tile
        int ps = p ^ hr;
        U4 u;
        u.w[0] = lds[(c8 * 4 + 0) * 128 + ps];
        u.w[1] = lds[(c8 * 4 + 1) * 128 + ps];
        u.w[2] = lds[(c8 * 4 + 2) * 128 + ps];
        u.w[3] = lds[(c8 * 4 + 3) * 128 + ps];
        size_t pix = ((size_t)(b * HH + y) * WW + bx * 128 + p);
        *(uint4*)(s0 + pix * 64 + c8 * 4) = u.v;   // 1KB contiguous per wave
    }
}

// =====================================================================
// ds_hwc: HWC s0 -> HWC d1/d2 (2x2 average in f32 of bf16 values).
// 16 lanes per output pixel; 4 x uint4 reads (256B segments), 1 store.
// =====================================================================
template <int SC>
__global__ __launch_bounds__(256) void ds_hwc(
        const unsigned int* __restrict__ s0f1, const unsigned int* __restrict__ s0f2,
        unsigned int* __restrict__ df1, unsigned int* __restrict__ df2) {
    constexpr int S = (SC == 1) ? 128 : 64;
    int z = blockIdx.y;        // 0..7 : (feat, b)
    int b = z & 3;
    const unsigned int* s0 = (z < 4 ? s0f1 : s0f2) + ((size_t)b * HH * WW) * 64;
    unsigned int* d = (z < 4 ? df1 : df2) + ((size_t)b * S * S) * 64;

    int tid = blockIdx.x * 256 + threadIdx.x;
    int c8 = tid & 15;
    int p = tid >> 4;          // output pixel 0..S*S-1
    int yo = p / S, xo = p % S;
    int yi = (SC == 1) ? 2 * yo : 4 * yo + 1;
    int xi = (SC == 1) ? 2 * xo : 4 * xo + 1;

    const unsigned int* p00 = s0 + ((size_t)(yi * WW + xi)) * 64 + c8 * 4;
    U4 a, bb, c, dd, o;
    a.v  = *(const uint4*)p00;
    bb.v = *(const uint4*)(p00 + 64);
    c.v  = *(const uint4*)(p00 + WW * 64);
    dd.v = *(const uint4*)(p00 + WW * 64 + 64);
#pragma unroll
    for (int j = 0; j < 4; ++j) {
        float lo = blo(a.w[j]) + blo(bb.w[j]) + blo(c.w[j]) + blo(dd.w[j]);
        float hi = bhi(a.w[j]) + bhi(bb.w[j]) + bhi(c.w[j]) + bhi(dd.w[j]);
        o.w[j] = pack_bf16(0.25f * lo, 0.25f * hi);
    }
    *(uint4*)(d + (size_t)p * 64 + c8 * 4) = o.v;
}

// =====================================================================
// HWC corr: 16 lanes per pixel, one uint4 (8 bf16 ch) per lane.
// =====================================================================
template <int SCALE>
__global__ void corr_hwc(const unsigned int* __restrict__ f1,
                         const unsigned int* __restrict__ f2,
                         const float* __restrict__ offs,
                         float* __restrict__ out) {
    constexpr int S = (SCALE == 0) ? 256 : (SCALE == 1 ? 128 : 64);
    constexpr int LOGS = (SCALE == 0) ? 8 : (SCALE == 1 ? 7 : 6);
    int tid = threadIdx.x;
    int lane = tid & 15;
    int pix = blockIdx.x * 16 + (tid >> 4);
    int b = pix >> (2 * LOGS);
    int p = pix & (S * S - 1);
    int y = p >> LOGS;
    int x = p & (S - 1);

    const float* offx = offs + ((size_t)b * 6 + 2 * SCALE) * (HH * WW);
    const float* offy = offx + HH * WW;
    float dx, dy;
    if constexpr (SCALE == 0) {
        dx = offx[y * WW + x];
        dy = offy[y * WW + x];
    } else if constexpr (SCALE == 1) {
        const float* px = offx + (2 * y) * WW + 2 * x;
        const float* py = offy + (2 * y) * WW + 2 * x;
        dx = 0.125f * (px[0] + px[1] + px[WW] + px[WW + 1]);
        dy = 0.125f * (py[0] + py[1] + py[WW] + py[WW + 1]);
    } else {
        const float* px = offx + (4 * y + 1) * WW + 4 * x + 1;
        const float* py = offy + (4 * y + 1) * WW + 4 * x + 1;
        dx = 0.0625f * (px[0] + px[1] + px[WW] + px[WW + 1]);
        dy = 0.0625f * (py[0] + py[1] + py[WW] + py[WW + 1]);
    }

    float sx = (float)x + dx;
    float sy = (float)y + dy;
    float x0f = floorf(sx), y0f = floorf(sy);
    float wx1 = sx - x0f, wy1 = sy - y0f;
    float wx0 = 1.0f - wx1, wy0 = 1.0f - wy1;
    int x0 = (int)x0f, y0 = (int)y0f;
    int x1 = x0 + 1, y1 = y0 + 1;
    bool vx0 = (x0 >= 0) & (x0 < S);
    bool vx1 = (x1 >= 0) & (x1 < S);
    bool vy0 = (y0 >= 0) & (y0 < S);
    bool vy1 = (y1 >= 0) & (y1 < S);
    float w00 = wy0 * wx0 * (float)(vy0 & vx0);
    float w01 = wy0 * wx1 * (float)(vy0 & vx1);
    float w10 = wy1 * wx0 * (float)(vy1 & vx0);
    float w11 = wy1 * wx1 * (float)(vy1 & vx1);
    int cx0 = min(max(x0, 0), S - 1), cx1 = min(max(x1, 0), S - 1);
    int cy0 = min(max(y0, 0), S - 1), cy1 = min(max(y1, 0), S - 1);
    size_t pb = (size_t)b << (2 * LOGS);
    size_t i00 = pb + (cy0 << LOGS) + cx0, i01 = pb + (cy0 << LOGS) + cx1;
    size_t i10 = pb + (cy1 << LOGS) + cx0, i11 = pb + (cy1 << LOGS) + cx1;

    int lo = lane * 4;
    U4 a, c00, c01, c10, c11;
    a.v   = *(const uint4*)(f1 + ((size_t)pix << 6) + lo);
    c00.v = *(const uint4*)(f2 + (i00 << 6) + lo);
    c01.v = *(const uint4*)(f2 + (i01 << 6) + lo);
    c10.v = *(const uint4*)(f2 + (i10 << 6) + lo);
    c11.v = *(const uint4*)(f2 + (i11 << 6) + lo);

    float acc = 0.0f;
#pragma unroll
    for (int j = 0; j < 4; ++j) {
        float s_lo = w00 * blo(c00.w[j]) + w01 * blo(c01.w[j]) + w10 * blo(c10.w[j]) + w11 * blo(c11.w[j]);
        float s_hi = w00 * bhi(c00.w[j]) + w01 * bhi(c01.w[j]) + w10 * bhi(c10.w[j]) + w11 * bhi(c11.w[j]);
        acc = fmaf(blo(a.w[j]), s_lo, acc);
        acc = fmaf(bhi(a.w[j]), s_hi, acc);
    }
    acc += __shfl_xor(acc, 8);
    acc += __shfl_xor(acc, 4);
    acc += __shfl_xor(acc, 2);
    acc += __shfl_xor(acc, 1);

    if (lane == 0) {
        if constexpr (SCALE == 0) {
            out[((size_t)b * 3) * (HH * WW) + p] = acc;
        } else {
            out[(size_t)b * (S * S) + p] = acc;
        }
    }
}

// ---------------- upsample corr back to 256x256 ----------------
template <int SCALE>
__global__ void up_kernel(const float* __restrict__ corr, float* __restrict__ out) {
    constexpr int S = (SCALE == 1) ? 128 : 64;
    constexpr float R = (float)S / 256.0f;
    int idx = blockIdx.x * blockDim.x + threadIdx.x;
    if (idx >= NB * HH * WW) return;
    int x = idx & 255;
    int t = idx >> 8;
    int y = t & 255;
    int b = t >> 8;
    float srcx = fminf(fmaxf(((float)x + 0.5f) * R - 0.5f, 0.0f), (float)(S - 1));
    float srcy = fminf(fmaxf(((float)y + 0.5f) * R - 0.5f, 0.0f), (float)(S - 1));
    int x0 = (int)srcx;
    int y0 = (int)srcy;
    int x1 = min(x0 + 1, S - 1), y1 = min(y0 + 1, S - 1);
    float wx = srcx - (float)x0, wy = srcy - (float)y0;
    const float* cp = corr + (size_t)b * (S * S);
    float v0 = cp[y0 * S + x0] * (1.0f - wx) + cp[y0 * S + x1] * wx;
    float v1 = cp[y1 * S + x0] * (1.0f - wx) + cp[y1 * S + x1] * wx;
    out[((size_t)b * 3 + SCALE) * (HH * WW) + y * WW + x] = (1.0f - wy) * v0 + wy * v1;
}

extern "C" void kernel_launch(void* const* d_in, const int* in_sizes, int n_in,
                              void* d_out, int out_size, void* d_ws, size_t ws_size,
                              hipStream_t stream) {
    const float* feat1 = (const float*)d_in[0];
    const float* feat2 = (const float*)d_in[1];
    const float* offs  = (const float*)d_in[2];
    float* out = (float*)d_out;

    const size_t n_s0 = (size_t)NB * HH * WW * 64;
    const size_t n_d1 = (size_t)NB * 128 * 128 * 64;
    const size_t n_d2 = (size_t)NB * 64 * 64 * 64;
    const size_t n_c1 = (size_t)NB * 128 * 128;
    const size_t n_c2 = (size_t)NB * 64 * 64;
    const size_t need = (2 * (n_s0 + n_d1 + n_d2) + n_c1 + n_c2) * 4;
    if (ws_size < need) return;

    unsigned int* ws = (unsigned int*)d_ws;
    unsigned int* s0f1 = ws;
    unsigned int* s0f2 = s0f1 + n_s0;
    unsigned int* d1f1 = s0f2 + n_s0;
    unsigned int* d1f2 = d1f1 + n_d1;
    unsigned int* d2f1 = d1f2 + n_d1;
    unsigned int* d2f2 = d2f1 + n_d2;
    float* corr1 = (float*)(d2f2 + n_d2);
    float* corr2 = corr1 + n_c1;

    prep5_kernel<<<dim3(2, 256, 8), 256, 0, stream>>>(feat1, feat2, s0f1, s0f2);

    ds_hwc<1><<<dim3(1024, 8), 256, 0, stream>>>(s0f1, s0f2, d1f1, d1f2);
    ds_hwc<2><<<dim3(256, 8), 256, 0, stream>>>(s0f1, s0f2, d2f1, d2f2);

    corr_hwc<0><<<NB * 65536 / 16, 256, 0, stream>>>(s0f1, s0f2, offs, out);
    corr_hwc<1><<<NB * 16384 / 16, 256, 0, stream>>>(d1f1, d1f2, offs, corr1);
    corr_hwc<2><<<NB * 4096 / 16, 256, 0, stream>>>(d2f1, d2f2, offs, corr2);

    up_kernel<1><<<(NB * HH * WW + 255) / 256, 256, 0, stream>>>(corr1, out);
    up_kernel<2><<<(NB * HH * WW + 255) / 256, 256, 0, stream>>>(corr2, out);
}

// Round 7
// 144.407 us; speedup vs baseline: 1.1071x; 1.0062x over previous
//
#include <hip/hip_runtime.h>

#define HH 256
#define WW 256
#define NB 4
#define NC 128
#define HW (HH * WW)

// ---------- bf16 helpers (manual, RNE) ----------
__device__ __forceinline__ float blo(unsigned int u) { return __uint_as_float(u << 16); }
__device__ __forceinline__ float bhi(unsigned int u) { return __uint_as_float(u & 0xffff0000u); }
__device__ __forceinline__ unsigned int bf16_rne(float f) {
    unsigned int u = __float_as_uint(f);
    return (u + 0x7fffu + ((u >> 16) & 1u)) >> 16;  // finite inputs only
}
__device__ __forceinline__ unsigned int pack_bf16(float a, float b) {
    return bf16_rne(a) | (bf16_rne(b) << 16);
}
union U4 { uint4 v; unsigned int w[4]; };

// =====================================================================
// prep6: CHW f32 -> HWC bf16 scale-0 ONLY. Same tiling as prep5
// (1 row x 128 cols x 128 ch), but ALL 16 global loads are issued into
// registers BEFORE any pack/LDS-write -> 16 loads in flight per wave
// (prep5 had ~2; VGPR_Count=44 proved per-iteration waitcnt).
// LDS: channel-major [cpair(64)][px(128)] uints, 32KB, bf16-packed.
// =====================================================================
__global__ __launch_bounds__(256) void prep6_kernel(
        const float* __restrict__ feat1, const float* __restrict__ feat2,
        unsigned int* __restrict__ s0f1, unsigned int* __restrict__ s0f2) {
    __shared__ unsigned int lds[64 * 128];   // 32 KB

    int z = blockIdx.z;
    int b = z & 3;
    const float* src = (z < 4 ? feat1 : feat2) + (size_t)b * NC * HW;
    unsigned int* s0 = (z < 4 ? s0f1 : s0f2);

    int y  = blockIdx.y;        // 0..255 : row
    int bx = blockIdx.x;        // 0..1   : 128-col half
    int tid = threadIdx.x;
    int w = tid >> 6;           // wave 0..3
    int l = tid & 63;
    int lp = l & 31;            // col float4 position (cols 4*lp..4*lp+3)
    int ch = l >> 5;            // sub-channel-pair select

    const float* rowp = src + (size_t)y * WW + bx * 128 + 4 * lp;

    // ---- phase 1a: issue ALL loads (held in registers, deep MLP) ----
    float4 va[8], vb[8];
#pragma unroll
    for (int it = 0; it < 8; ++it) {
        int cp = it * 8 + w * 2 + ch;          // channel pair 0..63
        const float* pa = rowp + (size_t)(2 * cp) * HW;
        va[it] = *(const float4*)pa;           // channel 2*cp
        vb[it] = *(const float4*)(pa + HW);    // channel 2*cp+1
    }
    // ---- phase 1b: pack + LDS write (waits drain progressively) ----
#pragma unroll
    for (int it = 0; it < 8; ++it) {
        int cp = it * 8 + w * 2 + ch;
        unsigned int h = ((cp >> 2) & 7) << 2;
        U4 u;
        u.w[0] = pack_bf16(va[it].x, vb[it].x);
        u.w[1] = pack_bf16(va[it].y, vb[it].y);
        u.w[2] = pack_bf16(va[it].z, vb[it].z);
        u.w[3] = pack_bf16(va[it].w, vb[it].w);
        *(uint4*)&lds[cp * 128 + ((4 * lp) ^ h)] = u.v;
    }
    __syncthreads();

    // ---- phase 2: read pixel vectors (2-way max), store linear HWC ----
    int c8 = l & 15;            // channel chunk (8 ch = 4 uints)
    int pq = l >> 4;            // 0..3
    int hr = (c8 & 7) << 2;
#pragma unroll
    for (int it = 0; it < 8; ++it) {
        int p = w * 32 + it * 4 + pq;          // pixel col within 128-tile
        int ps = p ^ hr;
        U4 u;
        u.w[0] = lds[(c8 * 4 + 0) * 128 + ps];
        u.w[1] = lds[(c8 * 4 + 1) * 128 + ps];
        u.w[2] = lds[(c8 * 4 + 2) * 128 + ps];
        u.w[3] = lds[(c8 * 4 + 3) * 128 + ps];
        size_t pix = ((size_t)(b * HH + y) * WW + bx * 128 + p);
        *(uint4*)(s0 + pix * 64 + c8 * 4) = u.v;   // 1KB contiguous per wave
    }
}

// =====================================================================
// ds_hwc: HWC s0 -> HWC d1/d2 (2x2 average in f32 of bf16 values).
// =====================================================================
template <int SC>
__global__ __launch_bounds__(256) void ds_hwc(
        const unsigned int* __restrict__ s0f1, const unsigned int* __restrict__ s0f2,
        unsigned int* __restrict__ df1, unsigned int* __restrict__ df2) {
    constexpr int S = (SC == 1) ? 128 : 64;
    int z = blockIdx.y;        // 0..7 : (feat, b)
    int b = z & 3;
    const unsigned int* s0 = (z < 4 ? s0f1 : s0f2) + ((size_t)b * HH * WW) * 64;
    unsigned int* d = (z < 4 ? df1 : df2) + ((size_t)b * S * S) * 64;

    int tid = blockIdx.x * 256 + threadIdx.x;
    int c8 = tid & 15;
    int p = tid >> 4;          // output pixel 0..S*S-1
    int yo = p / S, xo = p % S;
    int yi = (SC == 1) ? 2 * yo : 4 * yo + 1;
    int xi = (SC == 1) ? 2 * xo : 4 * xo + 1;

    const unsigned int* p00 = s0 + ((size_t)(yi * WW + xi)) * 64 + c8 * 4;
    U4 a, bb, c, dd, o;
    a.v  = *(const uint4*)p00;
    bb.v = *(const uint4*)(p00 + 64);
    c.v  = *(const uint4*)(p00 + WW * 64);
    dd.v = *(const uint4*)(p00 + WW * 64 + 64);
#pragma unroll
    for (int j = 0; j < 4; ++j) {
        float lo = blo(a.w[j]) + blo(bb.w[j]) + blo(c.w[j]) + blo(dd.w[j]);
        float hi = bhi(a.w[j]) + bhi(bb.w[j]) + bhi(c.w[j]) + bhi(dd.w[j]);
        o.w[j] = pack_bf16(0.25f * lo, 0.25f * hi);
    }
    *(uint4*)(d + (size_t)p * 64 + c8 * 4) = o.v;
}

// =====================================================================
// HWC corr: 16 lanes per pixel, one uint4 (8 bf16 ch) per lane.
// =====================================================================
template <int SCALE>
__global__ void corr_hwc(const unsigned int* __restrict__ f1,
                         const unsigned int* __restrict__ f2,
                         const float* __restrict__ offs,
                         float* __restrict__ out) {
    constexpr int S = (SCALE == 0) ? 256 : (SCALE == 1 ? 128 : 64);
    constexpr int LOGS = (SCALE == 0) ? 8 : (SCALE == 1 ? 7 : 6);
    int tid = threadIdx.x;
    int lane = tid & 15;
    int pix = blockIdx.x * 16 + (tid >> 4);
    int b = pix >> (2 * LOGS);
    int p = pix & (S * S - 1);
    int y = p >> LOGS;
    int x = p & (S - 1);

    const float* offx = offs + ((size_t)b * 6 + 2 * SCALE) * (HH * WW);
    const float* offy = offx + HH * WW;
    float dx, dy;
    if constexpr (SCALE == 0) {
        dx = offx[y * WW + x];
        dy = offy[y * WW + x];
    } else if constexpr (SCALE == 1) {
        const float* px = offx + (2 * y) * WW + 2 * x;
        const float* py = offy + (2 * y) * WW + 2 * x;
        dx = 0.125f * (px[0] + px[1] + px[WW] + px[WW + 1]);
        dy = 0.125f * (py[0] + py[1] + py[WW] + py[WW + 1]);
    } else {
        const float* px = offx + (4 * y + 1) * WW + 4 * x + 1;
        const float* py = offy + (4 * y + 1) * WW + 4 * x + 1;
        dx = 0.0625f * (px[0] + px[1] + px[WW] + px[WW + 1]);
        dy = 0.0625f * (py[0] + py[1] + py[WW] + py[WW + 1]);
    }

    float sx = (float)x + dx;
    float sy = (float)y + dy;
    float x0f = floorf(sx), y0f = floorf(sy);
    float wx1 = sx - x0f, wy1 = sy - y0f;
    float wx0 = 1.0f - wx1, wy0 = 1.0f - wy1;
    int x0 = (int)x0f, y0 = (int)y0f;
    int x1 = x0 + 1, y1 = y0 + 1;
    bool vx0 = (x0 >= 0) & (x0 < S);
    bool vx1 = (x1 >= 0) & (x1 < S);
    bool vy0 = (y0 >= 0) & (y0 < S);
    bool vy1 = (y1 >= 0) & (y1 < S);
    float w00 = wy0 * wx0 * (float)(vy0 & vx0);
    float w01 = wy0 * wx1 * (float)(vy0 & vx1);
    float w10 = wy1 * wx0 * (float)(vy1 & vx0);
    float w11 = wy1 * wx1 * (float)(vy1 & vx1);
    int cx0 = min(max(x0, 0), S - 1), cx1 = min(max(x1, 0), S - 1);
    int cy0 = min(max(y0, 0), S - 1), cy1 = min(max(y1, 0), S - 1);
    size_t pb = (size_t)b << (2 * LOGS);
    size_t i00 = pb + (cy0 << LOGS) + cx0, i01 = pb + (cy0 << LOGS) + cx1;
    size_t i10 = pb + (cy1 << LOGS) + cx0, i11 = pb + (cy1 << LOGS) + cx1;

    int lo = lane * 4;
    U4 a, c00, c01, c10, c11;
    a.v   = *(const uint4*)(f1 + ((size_t)pix << 6) + lo);
    c00.v = *(const uint4*)(f2 + (i00 << 6) + lo);
    c01.v = *(const uint4*)(f2 + (i01 << 6) + lo);
    c10.v = *(const uint4*)(f2 + (i10 << 6) + lo);
    c11.v = *(const uint4*)(f2 + (i11 << 6) + lo);

    float acc = 0.0f;
#pragma unroll
    for (int j = 0; j < 4; ++j) {
        float s_lo = w00 * blo(c00.w[j]) + w01 * blo(c01.w[j]) + w10 * blo(c10.w[j]) + w11 * blo(c11.w[j]);
        float s_hi = w00 * bhi(c00.w[j]) + w01 * bhi(c01.w[j]) + w10 * bhi(c10.w[j]) + w11 * bhi(c11.w[j]);
        acc = fmaf(blo(a.w[j]), s_lo, acc);
        acc = fmaf(bhi(a.w[j]), s_hi, acc);
    }
    acc += __shfl_xor(acc, 8);
    acc += __shfl_xor(acc, 4);
    acc += __shfl_xor(acc, 2);
    acc += __shfl_xor(acc, 1);

    if (lane == 0) {
        if constexpr (SCALE == 0) {
            out[((size_t)b * 3) * (HH * WW) + p] = acc;
        } else {
            out[(size_t)b * (S * S) + p] = acc;
        }
    }
}

// ---------------- upsample corr back to 256x256 ----------------
template <int SCALE>
__global__ void up_kernel(const float* __restrict__ corr, float* __restrict__ out) {
    constexpr int S = (SCALE == 1) ? 128 : 64;
    constexpr float R = (float)S / 256.0f;
    int idx = blockIdx.x * blockDim.x + threadIdx.x;
    if (idx >= NB * HH * WW) return;
    int x = idx & 255;
    int t = idx >> 8;
    int y = t & 255;
    int b = t >> 8;
    float srcx = fminf(fmaxf(((float)x + 0.5f) * R - 0.5f, 0.0f), (float)(S - 1));
    float srcy = fminf(fmaxf(((float)y + 0.5f) * R - 0.5f, 0.0f), (float)(S - 1));
    int x0 = (int)srcx;
    int y0 = (int)srcy;
    int x1 = min(x0 + 1, S - 1), y1 = min(y0 + 1, S - 1);
    float wx = srcx - (float)x0, wy = srcy - (float)y0;
    const float* cp = corr + (size_t)b * (S * S);
    float v0 = cp[y0 * S + x0] * (1.0f - wx) + cp[y0 * S + x1] * wx;
    float v1 = cp[y1 * S + x0] * (1.0f - wx) + cp[y1 * S + x1] * wx;
    out[((size_t)b * 3 + SCALE) * (HH * WW) + y * WW + x] = (1.0f - wy) * v0 + wy * v1;
}

extern "C" void kernel_launch(void* const* d_in, const int* in_sizes, int n_in,
                              void* d_out, int out_size, void* d_ws, size_t ws_size,
                              hipStream_t stream) {
    const float* feat1 = (const float*)d_in[0];
    const float* feat2 = (const float*)d_in[1];
    const float* offs  = (const float*)d_in[2];
    float* out = (float*)d_out;

    const size_t n_s0 = (size_t)NB * HH * WW * 64;
    const size_t n_d1 = (size_t)NB * 128 * 128 * 64;
    const size_t n_d2 = (size_t)NB * 64 * 64 * 64;
    const size_t n_c1 = (size_t)NB * 128 * 128;
    const size_t n_c2 = (size_t)NB * 64 * 64;
    const size_t need = (2 * (n_s0 + n_d1 + n_d2) + n_c1 + n_c2) * 4;
    if (ws_size < need) return;

    unsigned int* ws = (unsigned int*)d_ws;
    unsigned int* s0f1 = ws;
    unsigned int* s0f2 = s0f1 + n_s0;
    unsigned int* d1f1 = s0f2 + n_s0;
    unsigned int* d1f2 = d1f1 + n_d1;
    unsigned int* d2f1 = d1f2 + n_d1;
    unsigned int* d2f2 = d2f1 + n_d2;
    float* corr1 = (float*)(d2f2 + n_d2);
    float* corr2 = corr1 + n_c1;

    prep6_kernel<<<dim3(2, 256, 8), 256, 0, stream>>>(feat1, feat2, s0f1, s0f2);

    ds_hwc<1><<<dim3(1024, 8), 256, 0, stream>>>(s0f1, s0f2, d1f1, d1f2);
    ds_hwc<2><<<dim3(256, 8), 256, 0, stream>>>(s0f1, s0f2, d2f1, d2f2);

    corr_hwc<0><<<NB * 65536 / 16, 256, 0, stream>>>(s0f1, s0f2, offs, out);
    corr_hwc<1><<<NB * 16384 / 16, 256, 0, stream>>>(d1f1, d1f2, offs, corr1);
    corr_hwc<2><<<NB * 4096 / 16, 256, 0, stream>>>(d2f1, d2f2, offs, corr2);

    up_kernel<1><<<(NB * HH * WW + 255) / 256, 256, 0, stream>>>(corr1, out);
    up_kernel<2><<<(NB * HH * WW + 255) / 256, 256, 0, stream>>>(corr2, out);
}

// Round 8
// 143.637 us; speedup vs baseline: 1.1131x; 1.0054x over previous
//
#include <hip/hip_runtime.h>

#define HH 256
#define WW 256
#define NB 4
#define NC 128
#define HW (HH * WW)

// ---------- bf16 helpers (manual, RNE) ----------
__device__ __forceinline__ float blo(unsigned int u) { return __uint_as_float(u << 16); }
__device__ __forceinline__ float bhi(unsigned int u) { return __uint_as_float(u & 0xffff0000u); }
__device__ __forceinline__ unsigned int bf16_rne(float f) {
    unsigned int u = __float_as_uint(f);
    return (u + 0x7fffu + ((u >> 16) & 1u)) >> 16;  // finite inputs only
}
__device__ __forceinline__ unsigned int pack_bf16(float a, float b) {
    return bf16_rne(a) | (bf16_rne(b) << 16);
}
union U4 { uint4 v; unsigned int w[4]; };

// =====================================================================
// prep7: CHW f32 -> HWC bf16 scale-0. Staging via global_load_lds DMA
// (16 x 1KB async per wave, no VGPR round-trip, one drain at barrier).
// LDS: f32, channel-major; DMA writes linearly, so the bank swizzle is
// applied by permuting the per-lane GLOBAL source chunk (m173 pattern):
//   instr (cp): lane chunk cc fetches col-chunk cc ^ e, e=(cp>>2)&7
//   read:  f32 idx = c*128 + 4*((p>>2) ^ (c8&7)) + (p&3)  -> 2-way max
// =====================================================================
__global__ __launch_bounds__(256) void prep7_kernel(
        const float* __restrict__ feat1, const float* __restrict__ feat2,
        unsigned int* __restrict__ s0f1, unsigned int* __restrict__ s0f2) {
    __shared__ float lds[128 * 128];   // 64 KB

    int z = blockIdx.z;
    int b = z & 3;
    const float* src = (z < 4 ? feat1 : feat2) + (size_t)b * NC * HW;
    unsigned int* s0 = (z < 4 ? s0f1 : s0f2);

    int y  = blockIdx.y;        // 0..255 : row
    int bx = blockIdx.x;        // 0..1   : 128-col half
    int tid = threadIdx.x;
    int w = tid >> 6;           // wave 0..3
    int l = tid & 63;

    // ---- DMA phase: wave w stages channel pairs 16w..16w+15 ----
    {
        int half = l >> 5;          // 0: even channel of pair, 1: odd
        int cc = l & 31;            // 16B col-chunk id
        const float* rowbase = src + (size_t)y * WW + bx * 128;
#pragma unroll
        for (int k = 0; k < 16; ++k) {
            int cp = w * 16 + k;                 // channel pair 0..63
            int e = (cp >> 2) & 7;               // col-chunk swizzle
            int ch = 2 * cp + half;
            const float* g = rowbase + (size_t)ch * HW + 4 * (cc ^ e);
            __builtin_amdgcn_global_load_lds(
                (const __attribute__((address_space(1))) void*)g,
                (__attribute__((address_space(3))) void*)&lds[cp * 256],
                16, 0, 0);
        }
    }
    __syncthreads();

    // ---- read phase: pixel-vector gather (swizzled), pack, store HWC ----
    int c8 = l & 15;            // channel chunk: channels 8*c8..8*c8+7
    int pq = l >> 4;            // 0..3
    int e = c8 & 7;
#pragma unroll
    for (int it = 0; it < 8; ++it) {
        int p = w * 32 + it * 4 + pq;            // pixel col in 128-tile
        int col = 4 * (((p >> 2) ^ e)) + (p & 3);
        U4 u;
#pragma unroll
        for (int j = 0; j < 4; ++j) {
            float lo = lds[(8 * c8 + 2 * j) * 128 + col];
            float hi = lds[(8 * c8 + 2 * j + 1) * 128 + col];
            u.w[j] = pack_bf16(lo, hi);
        }
        size_t pix = ((size_t)(b * HH + y) * WW + bx * 128 + p);
        *(uint4*)(s0 + pix * 64 + c8 * 4) = u.v;   // 1KB contiguous per wave
    }
}

// =====================================================================
// ds_hwc: HWC s0 -> HWC d1/d2 (2x2 average in f32 of bf16 values).
// =====================================================================
template <int SC>
__global__ __launch_bounds__(256) void ds_hwc(
        const unsigned int* __restrict__ s0f1, const unsigned int* __restrict__ s0f2,
        unsigned int* __restrict__ df1, unsigned int* __restrict__ df2) {
    constexpr int S = (SC == 1) ? 128 : 64;
    int z = blockIdx.y;        // 0..7 : (feat, b)
    int b = z & 3;
    const unsigned int* s0 = (z < 4 ? s0f1 : s0f2) + ((size_t)b * HH * WW) * 64;
    unsigned int* d = (z < 4 ? df1 : df2) + ((size_t)b * S * S) * 64;

    int tid = blockIdx.x * 256 + threadIdx.x;
    int c8 = tid & 15;
    int p = tid >> 4;          // output pixel 0..S*S-1
    int yo = p / S, xo = p % S;
    int yi = (SC == 1) ? 2 * yo : 4 * yo + 1;
    int xi = (SC == 1) ? 2 * xo : 4 * xo + 1;

    const unsigned int* p00 = s0 + ((size_t)(yi * WW + xi)) * 64 + c8 * 4;
    U4 a, bb, c, dd, o;
    a.v  = *(const uint4*)p00;
    bb.v = *(const uint4*)(p00 + 64);
    c.v  = *(const uint4*)(p00 + WW * 64);
    dd.v = *(const uint4*)(p00 + WW * 64 + 64);
#pragma unroll
    for (int j = 0; j < 4; ++j) {
        float lo = blo(a.w[j]) + blo(bb.w[j]) + blo(c.w[j]) + blo(dd.w[j]);
        float hi = bhi(a.w[j]) + bhi(bb.w[j]) + bhi(c.w[j]) + bhi(dd.w[j]);
        o.w[j] = pack_bf16(0.25f * lo, 0.25f * hi);
    }
    *(uint4*)(d + (size_t)p * 64 + c8 * 4) = o.v;
}

// =====================================================================
// HWC corr: 16 lanes per pixel, one uint4 (8 bf16 ch) per lane.
// =====================================================================
template <int SCALE>
__global__ void corr_hwc(const unsigned int* __restrict__ f1,
                         const unsigned int* __restrict__ f2,
                         const float* __restrict__ offs,
                         float* __restrict__ out) {
    constexpr int S = (SCALE == 0) ? 256 : (SCALE == 1 ? 128 : 64);
    constexpr int LOGS = (SCALE == 0) ? 8 : (SCALE == 1 ? 7 : 6);
    int tid = threadIdx.x;
    int lane = tid & 15;
    int pix = blockIdx.x * 16 + (tid >> 4);
    int b = pix >> (2 * LOGS);
    int p = pix & (S * S - 1);
    int y = p >> LOGS;
    int x = p & (S - 1);

    const float* offx = offs + ((size_t)b * 6 + 2 * SCALE) * (HH * WW);
    const float* offy = offx + HH * WW;
    float dx, dy;
    if constexpr (SCALE == 0) {
        dx = offx[y * WW + x];
        dy = offy[y * WW + x];
    } else if constexpr (SCALE == 1) {
        const float* px = offx + (2 * y) * WW + 2 * x;
        const float* py = offy + (2 * y) * WW + 2 * x;
        dx = 0.125f * (px[0] + px[1] + px[WW] + px[WW + 1]);
        dy = 0.125f * (py[0] + py[1] + py[WW] + py[WW + 1]);
    } else {
        const float* px = offx + (4 * y + 1) * WW + 4 * x + 1;
        const float* py = offy + (4 * y + 1) * WW + 4 * x + 1;
        dx = 0.0625f * (px[0] + px[1] + px[WW] + px[WW + 1]);
        dy = 0.0625f * (py[0] + py[1] + py[WW] + py[WW + 1]);
    }

    float sx = (float)x + dx;
    float sy = (float)y + dy;
    float x0f = floorf(sx), y0f = floorf(sy);
    float wx1 = sx - x0f, wy1 = sy - y0f;
    float wx0 = 1.0f - wx1, wy0 = 1.0f - wy1;
    int x0 = (int)x0f, y0 = (int)y0f;
    int x1 = x0 + 1, y1 = y0 + 1;
    bool vx0 = (x0 >= 0) & (x0 < S);
    bool vx1 = (x1 >= 0) & (x1 < S);
    bool vy0 = (y0 >= 0) & (y0 < S);
    bool vy1 = (y1 >= 0) & (y1 < S);
    float w00 = wy0 * wx0 * (float)(vy0 & vx0);
    float w01 = wy0 * wx1 * (float)(vy0 & vx1);
    float w10 = wy1 * wx0 * (float)(vy1 & vx0);
    float w11 = wy1 * wx1 * (float)(vy1 & vx1);
    int cx0 = min(max(x0, 0), S - 1), cx1 = min(max(x1, 0), S - 1);
    int cy0 = min(max(y0, 0), S - 1), cy1 = min(max(y1, 0), S - 1);
    size_t pb = (size_t)b << (2 * LOGS);
    size_t i00 = pb + (cy0 << LOGS) + cx0, i01 = pb + (cy0 << LOGS) + cx1;
    size_t i10 = pb + (cy1 << LOGS) + cx0, i11 = pb + (cy1 << LOGS) + cx1;

    int lo = lane * 4;
    U4 a, c00, c01, c10, c11;
    a.v   = *(const uint4*)(f1 + ((size_t)pix << 6) + lo);
    c00.v = *(const uint4*)(f2 + (i00 << 6) + lo);
    c01.v = *(const uint4*)(f2 + (i01 << 6) + lo);
    c10.v = *(const uint4*)(f2 + (i10 << 6) + lo);
    c11.v = *(const uint4*)(f2 + (i11 << 6) + lo);

    float acc = 0.0f;
#pragma unroll
    for (int j = 0; j < 4; ++j) {
        float s_lo = w00 * blo(c00.w[j]) + w01 * blo(c01.w[j]) + w10 * blo(c10.w[j]) + w11 * blo(c11.w[j]);
        float s_hi = w00 * bhi(c00.w[j]) + w01 * bhi(c01.w[j]) + w10 * bhi(c10.w[j]) + w11 * bhi(c11.w[j]);
        acc = fmaf(blo(a.w[j]), s_lo, acc);
        acc = fmaf(bhi(a.w[j]), s_hi, acc);
    }
    acc += __shfl_xor(acc, 8);
    acc += __shfl_xor(acc, 4);
    acc += __shfl_xor(acc, 2);
    acc += __shfl_xor(acc, 1);

    if (lane == 0) {
        if constexpr (SCALE == 0) {
            out[((size_t)b * 3) * (HH * WW) + p] = acc;
        } else {
            out[(size_t)b * (S * S) + p] = acc;
        }
    }
}

// ---------------- upsample corr back to 256x256 ----------------
template <int SCALE>
__global__ void up_kernel(const float* __restrict__ corr, float* __restrict__ out) {
    constexpr int S = (SCALE == 1) ? 128 : 64;
    constexpr float R = (float)S / 256.0f;
    int idx = blockIdx.x * blockDim.x + threadIdx.x;
    if (idx >= NB * HH * WW) return;
    int x = idx & 255;
    int t = idx >> 8;
    int y = t & 255;
    int b = t >> 8;
    float srcx = fminf(fmaxf(((float)x + 0.5f) * R - 0.5f, 0.0f), (float)(S - 1));
    float srcy = fminf(fmaxf(((float)y + 0.5f) * R - 0.5f, 0.0f), (float)(S - 1));
    int x0 = (int)srcx;
    int y0 = (int)srcy;
    int x1 = min(x0 + 1, S - 1), y1 = min(y0 + 1, S - 1);
    float wx = srcx - (float)x0, wy = srcy - (float)y0;
    const float* cp = corr + (size_t)b * (S * S);
    float v0 = cp[y0 * S + x0] * (1.0f - wx) + cp[y0 * S + x1] * wx;
    float v1 = cp[y1 * S + x0] * (1.0f - wx) + cp[y1 * S + x1] * wx;
    out[((size_t)b * 3 + SCALE) * (HH * WW) + y * WW + x] = (1.0f - wy) * v0 + wy * v1;
}

extern "C" void kernel_launch(void* const* d_in, const int* in_sizes, int n_in,
                              void* d_out, int out_size, void* d_ws, size_t ws_size,
                              hipStream_t stream) {
    const float* feat1 = (const float*)d_in[0];
    const float* feat2 = (const float*)d_in[1];
    const float* offs  = (const float*)d_in[2];
    float* out = (float*)d_out;

    const size_t n_s0 = (size_t)NB * HH * WW * 64;
    const size_t n_d1 = (size_t)NB * 128 * 128 * 64;
    const size_t n_d2 = (size_t)NB * 64 * 64 * 64;
    const size_t n_c1 = (size_t)NB * 128 * 128;
    const size_t n_c2 = (size_t)NB * 64 * 64;
    const size_t need = (2 * (n_s0 + n_d1 + n_d2) + n_c1 + n_c2) * 4;
    if (ws_size < need) return;

    unsigned int* ws = (unsigned int*)d_ws;
    unsigned int* s0f1 = ws;
    unsigned int* s0f2 = s0f1 + n_s0;
    unsigned int* d1f1 = s0f2 + n_s0;
    unsigned int* d1f2 = d1f1 + n_d1;
    unsigned int* d2f1 = d1f2 + n_d1;
    unsigned int* d2f2 = d2f1 + n_d2;
    float* corr1 = (float*)(d2f2 + n_d2);
    float* corr2 = corr1 + n_c1;

    prep7_kernel<<<dim3(2, 256, 8), 256, 0, stream>>>(feat1, feat2, s0f1, s0f2);

    ds_hwc<1><<<dim3(1024, 8), 256, 0, stream>>>(s0f1, s0f2, d1f1, d1f2);
    ds_hwc<2><<<dim3(256, 8), 256, 0, stream>>>(s0f1, s0f2, d2f1, d2f2);

    corr_hwc<0><<<NB * 65536 / 16, 256, 0, stream>>>(s0f1, s0f2, offs, out);
    corr_hwc<1><<<NB * 16384 / 16, 256, 0, stream>>>(d1f1, d1f2, offs, corr1);
    corr_hwc<2><<<NB * 4096 / 16, 256, 0, stream>>>(d2f1, d2f2, offs, corr2);

    up_kernel<1><<<(NB * HH * WW + 255) / 256, 256, 0, stream>>>(corr1, out);
    up_kernel<2><<<(NB * HH * WW + 255) / 256, 256, 0, stream>>>(corr2, out);
}

// Round 9
// 139.522 us; speedup vs baseline: 1.1459x; 1.0295x over previous
//
#include <hip/hip_runtime.h>

#define HH 256
#define WW 256
#define NB 4
#define NC 128
#define HW (HH * WW)

// ---------- bf16 helpers (manual, RNE) ----------
__device__ __forceinline__ float blo(unsigned int u) { return __uint_as_float(u << 16); }
__device__ __forceinline__ float bhi(unsigned int u) { return __uint_as_float(u & 0xffff0000u); }
__device__ __forceinline__ unsigned int bf16_rne(float f) {
    unsigned int u = __float_as_uint(f);
    return (u + 0x7fffu + ((u >> 16) & 1u)) >> 16;  // finite inputs only
}
__device__ __forceinline__ unsigned int pack_bf16(float a, float b) {
    return bf16_rne(a) | (bf16_rne(b) << 16);
}
union U4 { uint4 v; unsigned int w[4]; };

// =====================================================================
// prep8: CHW f32 -> HWC bf16 scale-0 + fused d1 (2x2 avg).
// Tile = 2 rows x 256 cols x 32 channels  -> each channel read is a
// 2KB CONTIGUOUS run (tests the DRAM-run-length theory).
// LDS: channel-major pixel-pair words lds[ch][pp], stride 258 (pad 2):
//   write: ds_write_b64, consecutive lanes tile banks (conflict-free)
//   read:  b32, broadcast pairs + 2-way worst case
// Stores: 64B sectors per pixel (16 uints of the 64-uint vector) = HBM
// granule, complementary channel-groups fill the rest of each line.
// =====================================================================
__global__ __launch_bounds__(256) void prep8_kernel(
        const float* __restrict__ feat1, const float* __restrict__ feat2,
        unsigned int* __restrict__ s0f1, unsigned int* __restrict__ s0f2,
        unsigned int* __restrict__ d1f1, unsigned int* __restrict__ d1f2) {
    __shared__ unsigned int lds[32 * 258];   // 33 KB

    int z = blockIdx.y;          // 0..7 : (feat, b)
    int b = z & 3;
    const float* src = (z < 4 ? feat1 : feat2) + (size_t)b * NC * HW;
    unsigned int* s0 = (z < 4 ? s0f1 : s0f2);
    unsigned int* d1 = (z < 4 ? d1f1 : d1f2);

    int cg = blockIdx.x & 3;     // channel group: ch 32cg..32cg+31
    int y2 = blockIdx.x >> 2;    // 0..127 : rows 2y2, 2y2+1
    int tid = threadIdx.x;

    // ---- load + pack: 16 float4 per thread, 2KB contiguous per channel ----
    const float* base = src + (size_t)(32 * cg) * HW + y2 * 512;
#pragma unroll
    for (int i = 0; i < 16; ++i) {
        int f4 = i * 256 + tid;          // 0..4095
        int ch = f4 >> 7;                // local channel 0..31
        int pos = f4 & 127;              // float4 pos in 512-f32 run
        float4 v = *(const float4*)(base + (size_t)ch * HW + 4 * pos);
        unsigned int w0 = pack_bf16(v.x, v.y);   // pixel-pair 2pos
        unsigned int w1 = pack_bf16(v.z, v.w);   // pixel-pair 2pos+1
        *(uint2*)&lds[ch * 258 + 2 * pos] = make_uint2(w0, w1);
    }
    __syncthreads();

    // ---- s0 phase: 512 px x 4 quarter-stores (8 iters) ----
#pragma unroll
    for (int it = 0; it < 8; ++it) {
        int item = it * 256 + tid;       // 0..2047
        int q = item & 3;
        int p = item >> 2;               // tile pixel 0..511
        int pp = p >> 1, h = p & 1;
        U4 o;
#pragma unroll
        for (int j = 0; j < 4; ++j) {
            int u = 4 * q + j;           // local pair 0..15
            unsigned int wA = lds[(2 * u) * 258 + pp];
            unsigned int wB = lds[(2 * u + 1) * 258 + pp];
            o.w[j] = h ? ((wA >> 16) | (wB & 0xffff0000u))
                       : ((wA & 0xffffu) | (wB << 16));
        }
        int r = p >> 8, x = p & 255;
        size_t pix = ((size_t)(b * HH + 2 * y2 + r) * WW + x);
        *(uint4*)(s0 + pix * 64 + 16 * cg + 4 * q) = o.v;
    }

    // ---- d1 phase: 128 px x 4 quarter-stores (2 iters), 2x2 avg in f32 ----
#pragma unroll
    for (int it = 0; it < 2; ++it) {
        int item = it * 256 + tid;       // 0..511
        int q = item & 3;
        int xq = item >> 2;              // d1 col 0..127
        U4 o;
#pragma unroll
        for (int j = 0; j < 4; ++j) {
            int u = 4 * q + j;
            unsigned int a0 = lds[(2 * u) * 258 + xq];         // row0 px 2xq,2xq+1
            unsigned int a1 = lds[(2 * u) * 258 + 128 + xq];   // row1
            unsigned int b0 = lds[(2 * u + 1) * 258 + xq];
            unsigned int b1 = lds[(2 * u + 1) * 258 + 128 + xq];
            float avA = 0.25f * (blo(a0) + bhi(a0) + blo(a1) + bhi(a1));
            float avB = 0.25f * (blo(b0) + bhi(b0) + blo(b1) + bhi(b1));
            o.w[j] = pack_bf16(avA, avB);
        }
        size_t pix = ((size_t)(b * 128 + y2) * 128 + xq);
        *(uint4*)(d1 + pix * 64 + 16 * cg + 4 * q) = o.v;
    }
}

// =====================================================================
// ds_hwc<2>: HWC s0 -> HWC d2 (rows {4y+1,4y+2} x cols {4x+1,4x+2}).
// =====================================================================
template <int SC>
__global__ __launch_bounds__(256) void ds_hwc(
        const unsigned int* __restrict__ s0f1, const unsigned int* __restrict__ s0f2,
        unsigned int* __restrict__ df1, unsigned int* __restrict__ df2) {
    constexpr int S = (SC == 1) ? 128 : 64;
    int z = blockIdx.y;        // 0..7 : (feat, b)
    int b = z & 3;
    const unsigned int* s0 = (z < 4 ? s0f1 : s0f2) + ((size_t)b * HH * WW) * 64;
    unsigned int* d = (z < 4 ? df1 : df2) + ((size_t)b * S * S) * 64;

    int tid = blockIdx.x * 256 + threadIdx.x;
    int c8 = tid & 15;
    int p = tid >> 4;          // output pixel 0..S*S-1
    int yo = p / S, xo = p % S;
    int yi = (SC == 1) ? 2 * yo : 4 * yo + 1;
    int xi = (SC == 1) ? 2 * xo : 4 * xo + 1;

    const unsigned int* p00 = s0 + ((size_t)(yi * WW + xi)) * 64 + c8 * 4;
    U4 a, bb, c, dd, o;
    a.v  = *(const uint4*)p00;
    bb.v = *(const uint4*)(p00 + 64);
    c.v  = *(const uint4*)(p00 + WW * 64);
    dd.v = *(const uint4*)(p00 + WW * 64 + 64);
#pragma unroll
    for (int j = 0; j < 4; ++j) {
        float lo = blo(a.w[j]) + blo(bb.w[j]) + blo(c.w[j]) + blo(dd.w[j]);
        float hi = bhi(a.w[j]) + bhi(bb.w[j]) + bhi(c.w[j]) + bhi(dd.w[j]);
        o.w[j] = pack_bf16(0.25f * lo, 0.25f * hi);
    }
    *(uint4*)(d + (size_t)p * 64 + c8 * 4) = o.v;
}

// =====================================================================
// HWC corr: 16 lanes per pixel, one uint4 (8 bf16 ch) per lane.
// =====================================================================
template <int SCALE>
__global__ void corr_hwc(const unsigned int* __restrict__ f1,
                         const unsigned int* __restrict__ f2,
                         const float* __restrict__ offs,
                         float* __restrict__ out) {
    constexpr int S = (SCALE == 0) ? 256 : (SCALE == 1 ? 128 : 64);
    constexpr int LOGS = (SCALE == 0) ? 8 : (SCALE == 1 ? 7 : 6);
    int tid = threadIdx.x;
    int lane = tid & 15;
    int pix = blockIdx.x * 16 + (tid >> 4);
    int b = pix >> (2 * LOGS);
    int p = pix & (S * S - 1);
    int y = p >> LOGS;
    int x = p & (S - 1);

    const float* offx = offs + ((size_t)b * 6 + 2 * SCALE) * (HH * WW);
    const float* offy = offx + HH * WW;
    float dx, dy;
    if constexpr (SCALE == 0) {
        dx = offx[y * WW + x];
        dy = offy[y * WW + x];
    } else if constexpr (SCALE == 1) {
        const float* px = offx + (2 * y) * WW + 2 * x;
        const float* py = offy + (2 * y) * WW + 2 * x;
        dx = 0.125f * (px[0] + px[1] + px[WW] + px[WW + 1]);
        dy = 0.125f * (py[0] + py[1] + py[WW] + py[WW + 1]);
    } else {
        const float* px = offx + (4 * y + 1) * WW + 4 * x + 1;
        const float* py = offy + (4 * y + 1) * WW + 4 * x + 1;
        dx = 0.0625f * (px[0] + px[1] + px[WW] + px[WW + 1]);
        dy = 0.0625f * (py[0] + py[1] + py[WW] + py[WW + 1]);
    }

    float sx = (float)x + dx;
    float sy = (float)y + dy;
    float x0f = floorf(sx), y0f = floorf(sy);
    float wx1 = sx - x0f, wy1 = sy - y0f;
    float wx0 = 1.0f - wx1, wy0 = 1.0f - wy1;
    int x0 = (int)x0f, y0 = (int)y0f;
    int x1 = x0 + 1, y1 = y0 + 1;
    bool vx0 = (x0 >= 0) & (x0 < S);
    bool vx1 = (x1 >= 0) & (x1 < S);
    bool vy0 = (y0 >= 0) & (y0 < S);
    bool vy1 = (y1 >= 0) & (y1 < S);
    float w00 = wy0 * wx0 * (float)(vy0 & vx0);
    float w01 = wy0 * wx1 * (float)(vy0 & vx1);
    float w10 = wy1 * wx0 * (float)(vy1 & vx0);
    float w11 = wy1 * wx1 * (float)(vy1 & vx1);
    int cx0 = min(max(x0, 0), S - 1), cx1 = min(max(x1, 0), S - 1);
    int cy0 = min(max(y0, 0), S - 1), cy1 = min(max(y1, 0), S - 1);
    size_t pb = (size_t)b << (2 * LOGS);
    size_t i00 = pb + (cy0 << LOGS) + cx0, i01 = pb + (cy0 << LOGS) + cx1;
    size_t i10 = pb + (cy1 << LOGS) + cx0, i11 = pb + (cy1 << LOGS) + cx1;

    int lo = lane * 4;
    U4 a, c00, c01, c10, c11;
    a.v   = *(const uint4*)(f1 + ((size_t)pix << 6) + lo);
    c00.v = *(const uint4*)(f2 + (i00 << 6) + lo);
    c01.v = *(const uint4*)(f2 + (i01 << 6) + lo);
    c10.v = *(const uint4*)(f2 + (i10 << 6) + lo);
    c11.v = *(const uint4*)(f2 + (i11 << 6) + lo);

    float acc = 0.0f;
#pragma unroll
    for (int j = 0; j < 4; ++j) {
        float s_lo = w00 * blo(c00.w[j]) + w01 * blo(c01.w[j]) + w10 * blo(c10.w[j]) + w11 * blo(c11.w[j]);
        float s_hi = w00 * bhi(c00.w[j]) + w01 * bhi(c01.w[j]) + w10 * bhi(c10.w[j]) + w11 * bhi(c11.w[j]);
        acc = fmaf(blo(a.w[j]), s_lo, acc);
        acc = fmaf(bhi(a.w[j]), s_hi, acc);
    }
    acc += __shfl_xor(acc, 8);
    acc += __shfl_xor(acc, 4);
    acc += __shfl_xor(acc, 2);
    acc += __shfl_xor(acc, 1);

    if (lane == 0) {
        if constexpr (SCALE == 0) {
            out[((size_t)b * 3) * (HH * WW) + p] = acc;
        } else {
            out[(size_t)b * (S * S) + p] = acc;
        }
    }
}

// ---------------- upsample corr back to 256x256 ----------------
template <int SCALE>
__global__ void up_kernel(const float* __restrict__ corr, float* __restrict__ out) {
    constexpr int S = (SCALE == 1) ? 128 : 64;
    constexpr float R = (float)S / 256.0f;
    int idx = blockIdx.x * blockDim.x + threadIdx.x;
    if (idx >= NB * HH * WW) return;
    int x = idx & 255;
    int t = idx >> 8;
    int y = t & 255;
    int b = t >> 8;
    float srcx = fminf(fmaxf(((float)x + 0.5f) * R - 0.5f, 0.0f), (float)(S - 1));
    float srcy = fminf(fmaxf(((float)y + 0.5f) * R - 0.5f, 0.0f), (float)(S - 1));
    int x0 = (int)srcx;
    int y0 = (int)srcy;
    int x1 = min(x0 + 1, S - 1), y1 = min(y0 + 1, S - 1);
    float wx = srcx - (float)x0, wy = srcy - (float)y0;
    const float* cp = corr + (size_t)b * (S * S);
    float v0 = cp[y0 * S + x0] * (1.0f - wx) + cp[y0 * S + x1] * wx;
    float v1 = cp[y1 * S + x0] * (1.0f - wx) + cp[y1 * S + x1] * wx;
    out[((size_t)b * 3 + SCALE) * (HH * WW) + y * WW + x] = (1.0f - wy) * v0 + wy * v1;
}

extern "C" void kernel_launch(void* const* d_in, const int* in_sizes, int n_in,
                              void* d_out, int out_size, void* d_ws, size_t ws_size,
                              hipStream_t stream) {
    const float* feat1 = (const float*)d_in[0];
    const float* feat2 = (const float*)d_in[1];
    const float* offs  = (const float*)d_in[2];
    float* out = (float*)d_out;

    const size_t n_s0 = (size_t)NB * HH * WW * 64;
    const size_t n_d1 = (size_t)NB * 128 * 128 * 64;
    const size_t n_d2 = (size_t)NB * 64 * 64 * 64;
    const size_t n_c1 = (size_t)NB * 128 * 128;
    const size_t n_c2 = (size_t)NB * 64 * 64;
    const size_t need = (2 * (n_s0 + n_d1 + n_d2) + n_c1 + n_c2) * 4;
    if (ws_size < need) return;

    unsigned int* ws = (unsigned int*)d_ws;
    unsigned int* s0f1 = ws;
    unsigned int* s0f2 = s0f1 + n_s0;
    unsigned int* d1f1 = s0f2 + n_s0;
    unsigned int* d1f2 = d1f1 + n_d1;
    unsigned int* d2f1 = d1f2 + n_d1;
    unsigned int* d2f2 = d2f1 + n_d2;
    float* corr1 = (float*)(d2f2 + n_d2);
    float* corr2 = corr1 + n_c1;

    prep8_kernel<<<dim3(512, 8), 256, 0, stream>>>(feat1, feat2, s0f1, s0f2,
                                                   d1f1, d1f2);

    ds_hwc<2><<<dim3(256, 8), 256, 0, stream>>>(s0f1, s0f2, d2f1, d2f2);

    corr_hwc<0><<<NB * 65536 / 16, 256, 0, stream>>>(s0f1, s0f2, offs, out);
    corr_hwc<1><<<NB * 16384 / 16, 256, 0, stream>>>(d1f1, d1f2, offs, corr1);
    corr_hwc<2><<<NB * 4096 / 16, 256, 0, stream>>>(d2f1, d2f2, offs, corr2);

    up_kernel<1><<<(NB * HH * WW + 255) / 256, 256, 0, stream>>>(corr1, out);
    up_kernel<2><<<(NB * HH * WW + 255) / 256, 256, 0, stream>>>(corr2, out);
}

// Round 10
// 130.113 us; speedup vs baseline: 1.2288x; 1.0723x over previous
//
#include <hip/hip_runtime.h>

#define HH 256
#define WW 256
#define NB 4
#define NC 128
#define HW (HH * WW)

// ---------- bf16 helpers (manual, RNE) ----------
__device__ __forceinline__ float blo(unsigned int u) { return __uint_as_float(u << 16); }
__device__ __forceinline__ float bhi(unsigned int u) { return __uint_as_float(u & 0xffff0000u); }
__device__ __forceinline__ unsigned int bf16_rne(float f) {
    unsigned int u = __float_as_uint(f);
    return (u + 0x7fffu + ((u >> 16) & 1u)) >> 16;  // finite inputs only
}
__device__ __forceinline__ unsigned int pack_bf16(float a, float b) {
    return bf16_rne(a) | (bf16_rne(b) << 16);
}
union U4 { uint4 v; unsigned int w[4]; };

// =====================================================================
// prep9: prep7's proven DMA staging + per-row consume, extended to a
// ROW PAIR per block with fused d1 production (kills ds_hwc<1>'s 168MB).
// LDS: f32 channel-major, ch at lds[ch*128 + 4*(cc^e_dma)], e_dma =
// ((ch>>1)>>2)&7; DMA sources pre-swizzled (m173 pattern).
// Consume: thread owns (c8, pr); item m = it*16 + w*4 + pr handles the
// pixel pair (2m, 2m+1): col1 = col0+1, 8x b64 LDS reads (2-way max),
// two s0 uint4 stores, 8 f32 accumulators per item for d1.
// =====================================================================
__global__ __launch_bounds__(256) void prep9_kernel(
        const float* __restrict__ feat1, const float* __restrict__ feat2,
        unsigned int* __restrict__ s0f1, unsigned int* __restrict__ s0f2,
        unsigned int* __restrict__ d1f1, unsigned int* __restrict__ d1f2) {
    __shared__ float lds[128 * 128];   // 64 KB

    int z = blockIdx.z;
    int b = z & 3;
    const float* src = (z < 4 ? feat1 : feat2) + (size_t)b * NC * HW;
    unsigned int* s0 = (z < 4 ? s0f1 : s0f2);
    unsigned int* d1 = (z < 4 ? d1f1 : d1f2);

    int y2 = blockIdx.y;        // 0..127 : rows 2*y2, 2*y2+1
    int bx = blockIdx.x;        // 0..1   : 128-col half
    int tid = threadIdx.x;
    int w = tid >> 6;           // wave 0..3
    int l = tid & 63;

    // DMA lane roles
    int half = l >> 5;          // 0: even channel of pair, 1: odd
    int cc = l & 31;            // 16B col-chunk id
    // consume lane roles
    int c8 = l & 15;            // channel chunk (8 ch)
    int pr = l >> 4;            // 0..3 pair slot
    int e = c8 & 7;

    float accLo[4][4], accHi[4][4];
#pragma unroll
    for (int i = 0; i < 4; ++i)
#pragma unroll
        for (int j = 0; j < 4; ++j) { accLo[i][j] = 0.0f; accHi[i][j] = 0.0f; }

#pragma unroll
    for (int phase = 0; phase < 2; ++phase) {
        int row = 2 * y2 + phase;
        // ---- DMA: wave w stages channel pairs 16w..16w+15 (16 x 1KB) ----
        {
            const float* rowbase = src + (size_t)row * WW + bx * 128;
#pragma unroll
            for (int k = 0; k < 16; ++k) {
                int cp = w * 16 + k;
                int ed = (cp >> 2) & 7;
                int ch = 2 * cp + half;
                const float* g = rowbase + (size_t)ch * HW + 4 * (cc ^ ed);
                __builtin_amdgcn_global_load_lds(
                    (const __attribute__((address_space(1))) void*)g,
                    (__attribute__((address_space(3))) void*)&lds[cp * 256],
                    16, 0, 0);
            }
        }
        __syncthreads();

        // ---- consume: 4 items -> pixel pairs, s0 stores + d1 accum ----
        size_t rowpix = ((size_t)(b * HH + row) * WW + bx * 128);
#pragma unroll
        for (int it = 0; it < 4; ++it) {
            int m = it * 16 + w * 4 + pr;          // pair id 0..63
            int col0 = 4 * ((m >> 1) ^ e) + 2 * (m & 1);
            U4 u0, u1;
#pragma unroll
            for (int j = 0; j < 4; ++j) {
                int ch = 8 * c8 + 2 * j;
                float lo0 = lds[ch * 128 + col0];
                float lo1 = lds[ch * 128 + col0 + 1];
                float hi0 = lds[(ch + 1) * 128 + col0];
                float hi1 = lds[(ch + 1) * 128 + col0 + 1];
                u0.w[j] = pack_bf16(lo0, hi0);
                u1.w[j] = pack_bf16(lo1, hi1);
                accLo[it][j] += lo0 + lo1;
                accHi[it][j] += hi0 + hi1;
            }
            *(uint4*)(s0 + (rowpix + 2 * m) * 64 + c8 * 4) = u0.v;
            *(uint4*)(s0 + (rowpix + 2 * m + 1) * 64 + c8 * 4) = u1.v;
        }
        __syncthreads();   // all reads done before next phase's DMA overwrites
    }

    // ---- emit d1: 1KB contiguous per wave per it ----
    size_t d1row = ((size_t)(b * 128 + y2) * 128 + bx * 64);
#pragma unroll
    for (int it = 0; it < 4; ++it) {
        int m = it * 16 + w * 4 + pr;
        U4 o;
#pragma unroll
        for (int j = 0; j < 4; ++j)
            o.w[j] = pack_bf16(0.25f * accLo[it][j], 0.25f * accHi[it][j]);
        *(uint4*)(d1 + (d1row + m) * 64 + c8 * 4) = o.v;
    }
}

// =====================================================================
// ds_hwc<2>: HWC s0 -> HWC d2 (rows {4y+1,4y+2} x cols {4x+1,4x+2}).
// =====================================================================
template <int SC>
__global__ __launch_bounds__(256) void ds_hwc(
        const unsigned int* __restrict__ s0f1, const unsigned int* __restrict__ s0f2,
        unsigned int* __restrict__ df1, unsigned int* __restrict__ df2) {
    constexpr int S = (SC == 1) ? 128 : 64;
    int z = blockIdx.y;        // 0..7 : (feat, b)
    int b = z & 3;
    const unsigned int* s0 = (z < 4 ? s0f1 : s0f2) + ((size_t)b * HH * WW) * 64;
    unsigned int* d = (z < 4 ? df1 : df2) + ((size_t)b * S * S) * 64;

    int tid = blockIdx.x * 256 + threadIdx.x;
    int c8 = tid & 15;
    int p = tid >> 4;          // output pixel 0..S*S-1
    int yo = p / S, xo = p % S;
    int yi = (SC == 1) ? 2 * yo : 4 * yo + 1;
    int xi = (SC == 1) ? 2 * xo : 4 * xo + 1;

    const unsigned int* p00 = s0 + ((size_t)(yi * WW + xi)) * 64 + c8 * 4;
    U4 a, bb, c, dd, o;
    a.v  = *(const uint4*)p00;
    bb.v = *(const uint4*)(p00 + 64);
    c.v  = *(const uint4*)(p00 + WW * 64);
    dd.v = *(const uint4*)(p00 + WW * 64 + 64);
#pragma unroll
    for (int j = 0; j < 4; ++j) {
        float lo = blo(a.w[j]) + blo(bb.w[j]) + blo(c.w[j]) + blo(dd.w[j]);
        float hi = bhi(a.w[j]) + bhi(bb.w[j]) + bhi(c.w[j]) + bhi(dd.w[j]);
        o.w[j] = pack_bf16(0.25f * lo, 0.25f * hi);
    }
    *(uint4*)(d + (size_t)p * 64 + c8 * 4) = o.v;
}

// =====================================================================
// HWC corr: 16 lanes per pixel, one uint4 (8 bf16 ch) per lane.
// =====================================================================
template <int SCALE>
__global__ void corr_hwc(const unsigned int* __restrict__ f1,
                         const unsigned int* __restrict__ f2,
                         const float* __restrict__ offs,
                         float* __restrict__ out) {
    constexpr int S = (SCALE == 0) ? 256 : (SCALE == 1 ? 128 : 64);
    constexpr int LOGS = (SCALE == 0) ? 8 : (SCALE == 1 ? 7 : 6);
    int tid = threadIdx.x;
    int lane = tid & 15;
    int pix = blockIdx.x * 16 + (tid >> 4);
    int b = pix >> (2 * LOGS);
    int p = pix & (S * S - 1);
    int y = p >> LOGS;
    int x = p & (S - 1);

    const float* offx = offs + ((size_t)b * 6 + 2 * SCALE) * (HH * WW);
    const float* offy = offx + HH * WW;
    float dx, dy;
    if constexpr (SCALE == 0) {
        dx = offx[y * WW + x];
        dy = offy[y * WW + x];
    } else if constexpr (SCALE == 1) {
        const float* px = offx + (2 * y) * WW + 2 * x;
        const float* py = offy + (2 * y) * WW + 2 * x;
        dx = 0.125f * (px[0] + px[1] + px[WW] + px[WW + 1]);
        dy = 0.125f * (py[0] + py[1] + py[WW] + py[WW + 1]);
    } else {
        const float* px = offx + (4 * y + 1) * WW + 4 * x + 1;
        const float* py = offy + (4 * y + 1) * WW + 4 * x + 1;
        dx = 0.0625f * (px[0] + px[1] + px[WW] + px[WW + 1]);
        dy = 0.0625f * (py[0] + py[1] + py[WW] + py[WW + 1]);
    }

    float sx = (float)x + dx;
    float sy = (float)y + dy;
    float x0f = floorf(sx), y0f = floorf(sy);
    float wx1 = sx - x0f, wy1 = sy - y0f;
    float wx0 = 1.0f - wx1, wy0 = 1.0f - wy1;
    int x0 = (int)x0f, y0 = (int)y0f;
    int x1 = x0 + 1, y1 = y0 + 1;
    bool vx0 = (x0 >= 0) & (x0 < S);
    bool vx1 = (x1 >= 0) & (x1 < S);
    bool vy0 = (y0 >= 0) & (y0 < S);
    bool vy1 = (y1 >= 0) & (y1 < S);
    float w00 = wy0 * wx0 * (float)(vy0 & vx0);
    float w01 = wy0 * wx1 * (float)(vy0 & vx1);
    float w10 = wy1 * wx0 * (float)(vy1 & vx0);
    float w11 = wy1 * wx1 * (float)(vy1 & vx1);
    int cx0 = min(max(x0, 0), S - 1), cx1 = min(max(x1, 0), S - 1);
    int cy0 = min(max(y0, 0), S - 1), cy1 = min(max(y1, 0), S - 1);
    size_t pb = (size_t)b << (2 * LOGS);
    size_t i00 = pb + (cy0 << LOGS) + cx0, i01 = pb + (cy0 << LOGS) + cx1;
    size_t i10 = pb + (cy1 << LOGS) + cx0, i11 = pb + (cy1 << LOGS) + cx1;

    int lo = lane * 4;
    U4 a, c00, c01, c10, c11;
    a.v   = *(const uint4*)(f1 + ((size_t)pix << 6) + lo);
    c00.v = *(const uint4*)(f2 + (i00 << 6) + lo);
    c01.v = *(const uint4*)(f2 + (i01 << 6) + lo);
    c10.v = *(const uint4*)(f2 + (i10 << 6) + lo);
    c11.v = *(const uint4*)(f2 + (i11 << 6) + lo);

    float acc = 0.0f;
#pragma unroll
    for (int j = 0; j < 4; ++j) {
        float s_lo = w00 * blo(c00.w[j]) + w01 * blo(c01.w[j]) + w10 * blo(c10.w[j]) + w11 * blo(c11.w[j]);
        float s_hi = w00 * bhi(c00.w[j]) + w01 * bhi(c01.w[j]) + w10 * bhi(c10.w[j]) + w11 * bhi(c11.w[j]);
        acc = fmaf(blo(a.w[j]), s_lo, acc);
        acc = fmaf(bhi(a.w[j]), s_hi, acc);
    }
    acc += __shfl_xor(acc, 8);
    acc += __shfl_xor(acc, 4);
    acc += __shfl_xor(acc, 2);
    acc += __shfl_xor(acc, 1);

    if (lane == 0) {
        if constexpr (SCALE == 0) {
            out[((size_t)b * 3) * (HH * WW) + p] = acc;
        } else {
            out[(size_t)b * (S * S) + p] = acc;
        }
    }
}

// ---------------- upsample corr back to 256x256 ----------------
template <int SCALE>
__global__ void up_kernel(const float* __restrict__ corr, float* __restrict__ out) {
    constexpr int S = (SCALE == 1) ? 128 : 64;
    constexpr float R = (float)S / 256.0f;
    int idx = blockIdx.x * blockDim.x + threadIdx.x;
    if (idx >= NB * HH * WW) return;
    int x = idx & 255;
    int t = idx >> 8;
    int y = t & 255;
    int b = t >> 8;
    float srcx = fminf(fmaxf(((float)x + 0.5f) * R - 0.5f, 0.0f), (float)(S - 1));
    float srcy = fminf(fmaxf(((float)y + 0.5f) * R - 0.5f, 0.0f), (float)(S - 1));
    int x0 = (int)srcx;
    int y0 = (int)srcy;
    int x1 = min(x0 + 1, S - 1), y1 = min(y0 + 1, S - 1);
    float wx = srcx - (float)x0, wy = srcy - (float)y0;
    const float* cp = corr + (size_t)b * (S * S);
    float v0 = cp[y0 * S + x0] * (1.0f - wx) + cp[y0 * S + x1] * wx;
    float v1 = cp[y1 * S + x0] * (1.0f - wx) + cp[y1 * S + x1] * wx;
    out[((size_t)b * 3 + SCALE) * (HH * WW) + y * WW + x] = (1.0f - wy) * v0 + wy * v1;
}

extern "C" void kernel_launch(void* const* d_in, const int* in_sizes, int n_in,
                              void* d_out, int out_size, void* d_ws, size_t ws_size,
                              hipStream_t stream) {
    const float* feat1 = (const float*)d_in[0];
    const float* feat2 = (const float*)d_in[1];
    const float* offs  = (const float*)d_in[2];
    float* out = (float*)d_out;

    const size_t n_s0 = (size_t)NB * HH * WW * 64;
    const size_t n_d1 = (size_t)NB * 128 * 128 * 64;
    const size_t n_d2 = (size_t)NB * 64 * 64 * 64;
    const size_t n_c1 = (size_t)NB * 128 * 128;
    const size_t n_c2 = (size_t)NB * 64 * 64;
    const size_t need = (2 * (n_s0 + n_d1 + n_d2) + n_c1 + n_c2) * 4;
    if (ws_size < need) return;

    unsigned int* ws = (unsigned int*)d_ws;
    unsigned int* s0f1 = ws;
    unsigned int* s0f2 = s0f1 + n_s0;
    unsigned int* d1f1 = s0f2 + n_s0;
    unsigned int* d1f2 = d1f1 + n_d1;
    unsigned int* d2f1 = d1f2 + n_d1;
    unsigned int* d2f2 = d2f1 + n_d2;
    float* corr1 = (float*)(d2f2 + n_d2);
    float* corr2 = corr1 + n_c1;

    prep9_kernel<<<dim3(2, 128, 8), 256, 0, stream>>>(feat1, feat2, s0f1, s0f2,
                                                      d1f1, d1f2);

    ds_hwc<2><<<dim3(256, 8), 256, 0, stream>>>(s0f1, s0f2, d2f1, d2f2);

    corr_hwc<0><<<NB * 65536 / 16, 256, 0, stream>>>(s0f1, s0f2, offs, out);
    corr_hwc<1><<<NB * 16384 / 16, 256, 0, stream>>>(d1f1, d1f2, offs, corr1);
    corr_hwc<2><<<NB * 4096 / 16, 256, 0, stream>>>(d2f1, d2f2, offs, corr2);

    up_kernel<1><<<(NB * HH * WW + 255) / 256, 256, 0, stream>>>(corr1, out);
    up_kernel<2><<<(NB * HH * WW + 255) / 256, 256, 0, stream>>>(corr2, out);
}